// Round 1
// baseline (2245.215 us; speedup 1.0000x reference)
//
#include <hip/hip_runtime.h>
#include <stdint.h>

typedef __bf16 bf16x8 __attribute__((ext_vector_type(8)));
typedef float  f32x4  __attribute__((ext_vector_type(4)));
typedef unsigned short ushortx4 __attribute__((ext_vector_type(4)));

#define LDS_NFROW 0
#define LDS_NFT   32768
#define LDS_P     65536
#define LDS_SAT   98304
#define LDS_RSA   131072
#define LDS_GB2   131584
#define LDS_BIH   133120
#define LDS_BHH   134656
#define LDS_MB1   136192
#define LDS_MB2   136704
#define LDS_TOTAL 137216

// ws layout (bytes)
#define WS_GW2T   0        // bf16 [384][128]
#define WS_WHH    98304    // bf16 [384][128]
#define WS_MW1    196608   // bf16 [128][128]
#define WS_MW2    229376   // bf16 [128][128]
#define WS_GB2    262144   // f32  [384]

__device__ __forceinline__ unsigned short f2bf(float f){
  union{float f; uint32_t u;} v; v.f = f;
  return (unsigned short)((v.u + 0x7FFFu + ((v.u>>16)&1u)) >> 16);
}
__device__ __forceinline__ float bf2f(unsigned short h){
  union{uint32_t u; float f;} v; v.u = ((uint32_t)h)<<16; return v.f;
}
__device__ __forceinline__ float fast_sigmoid(float x){
  float t = __builtin_amdgcn_exp2f(-1.442695041f*x);
  return __builtin_amdgcn_rcpf(1.0f + t);
}
__device__ __forceinline__ float fast_tanh(float x){
  float t = __builtin_amdgcn_exp2f(-2.885390082f*x);
  return 2.0f*__builtin_amdgcn_rcpf(1.0f + t) - 1.0f;
}
// XOR-swizzled row-major [128][128] bf16 LDS addressing. 16B chunks of 8 elems,
// chunk index ^= (row&7): conflict-free b128 frag reads, b64 half-chunk writes.
__device__ __forceinline__ uint32_t sw(uint32_t row, uint32_t col){
  return row*256u + ((((col>>3) ^ (row&7)) << 4) | ((col&7)<<1));
}

// ---------------- prep kernel: weight conversions + Gw2T + gb2 ----------------
extern "C" __global__ __launch_bounds__(128) void gnn_prep(
    const float* __restrict__ Wih, const float* __restrict__ Whh,
    const float* __restrict__ gnnw, const float* __restrict__ gnnb,
    const float* __restrict__ mW1, const float* __restrict__ mW2,
    unsigned short* __restrict__ gw2t, unsigned short* __restrict__ whhb,
    unsigned short* __restrict__ mw1b, unsigned short* __restrict__ mw2b,
    float* __restrict__ gb2)
{
  __shared__ float wg[128];
  const int b = blockIdx.x, t = threadIdx.x;
  if (b < 384){
    // Gw2T[g][t] = sum_h Wih[g][h] * gnnw[t][h]   (g = b)
    wg[t] = Wih[b*128 + t];
    __syncthreads();
    float acc = 0.f;
    for (int h=0; h<128; ++h) acc += wg[h] * gnnw[t*128 + h];
    gw2t[b*128 + t] = f2bf(acc);
    if (t == 0){
      float a2 = 0.f;
      for (int h=0; h<128; ++h) a2 += wg[h] * gnnb[h];
      gb2[b] = a2;
    }
  } else if (b < 416){
    int base = (b-384)*1536;
    for (int i=t; i<1536; i+=128) whhb[base+i] = f2bf(Whh[base+i]);
  } else if (b < 432){
    int base = (b-416)*1024;
    for (int i=t; i<1024; i+=128) mw1b[base+i] = f2bf(mW1[base+i]);
  } else if (b < 448){
    int base = (b-432)*1024;
    for (int i=t; i<1024; i+=128) mw2b[base+i] = f2bf(mW2[base+i]);
  }
}

// ---------------- main fused kernel: one block per (b,s) sentence ----------------
extern "C" __global__ __launch_bounds__(512) void gnn_main(
    const int* __restrict__ iv, const float* __restrict__ adj,
    const float* __restrict__ emb,
    const float* __restrict__ bih, const float* __restrict__ bhh,
    const float* __restrict__ mb1, const float* __restrict__ mb2,
    const float* __restrict__ mW3, const float* __restrict__ mb3,
    const __bf16* __restrict__ gw2t, const __bf16* __restrict__ whhb,
    const __bf16* __restrict__ mw1b, const __bf16* __restrict__ mw2b,
    const float* __restrict__ gb2, float* __restrict__ out)
{
  extern __shared__ char lds[];
  const int bs   = blockIdx.x;
  const int tid  = threadIdx.x;
  const int w    = tid >> 6;
  const int lane = tid & 63;
  const int n16  = lane & 15;
  const int q    = lane >> 4;
  const f32x4 zf4 = {0.f, 0.f, 0.f, 0.f};

  // ---- biases -> LDS ----
  if (tid < 384){
    *(float*)(lds + LDS_GB2 + tid*4) = gb2[tid];
    *(float*)(lds + LDS_BIH + tid*4) = bih[tid];
    *(float*)(lds + LDS_BHH + tid*4) = bhh[tid];
  }
  if (tid >= 384){
    int t = tid - 384;
    *(float*)(lds + LDS_MB1 + t*4) = mb1[t];
    *(float*)(lds + LDS_MB2 + t*4) = mb2[t];
  }

  // ---- gather emb rows -> nf_row (b128) + nfT (u16 scatter) ----
  {
    const int l  = tid >> 2;
    const int hc = (tid & 3) * 32;
    const int row = iv[bs*128 + l];
    const float* src = emb + (size_t)row*128 + hc;
    #pragma unroll
    for (int c=0; c<4; ++c){
      float4 f0 = *(const float4*)(src + c*8);
      float4 f1 = *(const float4*)(src + c*8 + 4);
      union{ bf16x8 v; unsigned short s8[8]; } u;
      u.s8[0]=f2bf(f0.x); u.s8[1]=f2bf(f0.y); u.s8[2]=f2bf(f0.z); u.s8[3]=f2bf(f0.w);
      u.s8[4]=f2bf(f1.x); u.s8[5]=f2bf(f1.y); u.s8[6]=f2bf(f1.z); u.s8[7]=f2bf(f1.w);
      *(bf16x8*)(lds + LDS_NFROW + sw(l, hc + c*8)) = u.v;
      #pragma unroll
      for (int j=0; j<8; ++j)
        *(unsigned short*)(lds + LDS_NFT + sw(hc + c*8 + j, l)) = u.s8[j];
    }
  }

  // ---- pack adjacency into MFMA B-fragment order (A^T B-operand) + row sums ----
  {
    const float* abase = adj + (size_t)bs * 16384;
    #pragma unroll
    for (int k=0; k<4; ++k){
      int s   = k*512 + tid;
      int sl  = s & 63;
      int chk = s >> 6;            // = ltile*4 + kstep
      int ltg = chk >> 2, ks = chk & 3;
      int al  = ltg*16 + (sl & 15);      // n-index -> A row l
      int ak  = ks*32 + (sl >> 4) * 8;   // k-index -> A col l'
      const float* p = abase + al*128 + ak;
      float4 f0 = *(const float4*)(p);
      float4 f1 = *(const float4*)(p + 4);
      union{ bf16x8 v; unsigned short s8[8]; } u;
      u.s8[0]=f2bf(f0.x); u.s8[1]=f2bf(f0.y); u.s8[2]=f2bf(f0.z); u.s8[3]=f2bf(f0.w);
      u.s8[4]=f2bf(f1.x); u.s8[5]=f2bf(f1.y); u.s8[6]=f2bf(f1.z); u.s8[7]=f2bf(f1.w);
      *(bf16x8*)(lds + LDS_SAT + s*16) = u.v;
    }
    int l = tid >> 2, p4 = tid & 3;
    const float* p = abase + l*128 + p4*32;
    float ssum = 0.f;
    #pragma unroll
    for (int c=0; c<8; ++c){
      float4 f = *(const float4*)(p + c*4);
      ssum += f.x + f.y + f.z + f.w;
    }
    ssum += __shfl_xor(ssum, 1);
    ssum += __shfl_xor(ssum, 2);
    if (p4 == 0) *(float*)(lds + LDS_RSA + l*4) = ssum;
  }
  __syncthreads();

  const int wr = w & 1, wc = w >> 1;
  const int t0 = wr*64, l0 = wc*32;   // stage-A / MLP tile origin
  const int h0 = w*16;                // GRU h-block for this wave

  const __bf16* gAr = gw2t + (size_t)(h0       + n16) * 128;
  const __bf16* gAz = gw2t + (size_t)(h0 + 128 + n16) * 128;
  const __bf16* gAn = gw2t + (size_t)(h0 + 256 + n16) * 128;
  const __bf16* hAr = whhb + (size_t)(h0       + n16) * 128;
  const __bf16* hAz = whhb + (size_t)(h0 + 128 + n16) * 128;
  const __bf16* hAn = whhb + (size_t)(h0 + 256 + n16) * 128;

  for (int it=0; it<10; ++it){
    // ===== stage A: P = A@nf, computed as P^T = nf^T @ A^T =====
    f32x4 accA[4][2];
    #pragma unroll
    for (int a=0; a<4; ++a){ accA[a][0] = zf4; accA[a][1] = zf4; }
    for (int ks=0; ks<4; ++ks){
      bf16x8 af[4];
      #pragma unroll
      for (int tt=0; tt<4; ++tt)
        af[tt] = *(const bf16x8*)(lds + LDS_NFT + sw(t0 + tt*16 + n16, ks*32 + q*8));
      #pragma unroll
      for (int lb=0; lb<2; ++lb){
        int chunk = (wc*2 + lb)*4 + ks;
        bf16x8 bfb = *(const bf16x8*)(lds + LDS_SAT + (chunk*64 + lane)*16);
        #pragma unroll
        for (int tt=0; tt<4; ++tt)
          accA[tt][lb] = __builtin_amdgcn_mfma_f32_16x16x32_bf16(af[tt], bfb, accA[tt][lb], 0,0,0);
      }
    }
    #pragma unroll
    for (int tt=0; tt<4; ++tt){
      #pragma unroll
      for (int lb=0; lb<2; ++lb){
        int l  = l0 + lb*16 + n16;
        int tb = t0 + tt*16 + q*4;
        ushortx4 o4;
        #pragma unroll
        for (int r=0; r<4; ++r) o4[r] = f2bf(accA[tt][lb][r]);
        *(ushortx4*)(lds + LDS_P + sw(l, tb)) = o4;   // P_row[l][t]
      }
    }
    __syncthreads();

    // ===== GRU gate matmuls (transposed: weights = A-op from L2, P/nf = B-op from LDS) =====
    f32x4 aR[8], aZ[8], aGN[8], aHN[8];
    #pragma unroll
    for (int i=0; i<8; ++i){ aR[i]=zf4; aZ[i]=zf4; aGN[i]=zf4; aHN[i]=zf4; }
    for (int ks=0; ks<4; ++ks){
      int koff = ks*32 + q*8;
      bf16x8 f_gr = *(const bf16x8*)(gAr + koff);
      bf16x8 f_gz = *(const bf16x8*)(gAz + koff);
      bf16x8 f_gn = *(const bf16x8*)(gAn + koff);
      bf16x8 f_hr = *(const bf16x8*)(hAr + koff);
      bf16x8 f_hz = *(const bf16x8*)(hAz + koff);
      bf16x8 f_hn = *(const bf16x8*)(hAn + koff);
      #pragma unroll
      for (int lt=0; lt<8; ++lt){
        int l = lt*16 + n16;
        bf16x8 bp = *(const bf16x8*)(lds + LDS_P     + sw(l, koff));
        bf16x8 bh = *(const bf16x8*)(lds + LDS_NFROW + sw(l, koff));
        aR[lt]  = __builtin_amdgcn_mfma_f32_16x16x32_bf16(f_gr, bp, aR[lt], 0,0,0);
        aR[lt]  = __builtin_amdgcn_mfma_f32_16x16x32_bf16(f_hr, bh, aR[lt], 0,0,0);
        aZ[lt]  = __builtin_amdgcn_mfma_f32_16x16x32_bf16(f_gz, bp, aZ[lt], 0,0,0);
        aZ[lt]  = __builtin_amdgcn_mfma_f32_16x16x32_bf16(f_hz, bh, aZ[lt], 0,0,0);
        aGN[lt] = __builtin_amdgcn_mfma_f32_16x16x32_bf16(f_gn, bp, aGN[lt], 0,0,0);
        aHN[lt] = __builtin_amdgcn_mfma_f32_16x16x32_bf16(f_hn, bh, aHN[lt], 0,0,0);
      }
    }
    __syncthreads();   // all reads of nf_row / P done before updates

    // ===== elementwise GRU update =====
    float c_gr[4], c_gz[4], c_gn[4], c_br[4], c_bz[4], c_bin[4], c_bhn[4];
    #pragma unroll
    for (int r=0; r<4; ++r){
      int h = h0 + q*4 + r;
      c_gr[r]  = *(const float*)(lds + LDS_GB2 + h*4);
      c_gz[r]  = *(const float*)(lds + LDS_GB2 + (128+h)*4);
      c_gn[r]  = *(const float*)(lds + LDS_GB2 + (256+h)*4);
      c_br[r]  = *(const float*)(lds + LDS_BIH + h*4)       + *(const float*)(lds + LDS_BHH + h*4);
      c_bz[r]  = *(const float*)(lds + LDS_BIH + (128+h)*4) + *(const float*)(lds + LDS_BHH + (128+h)*4);
      c_bin[r] = *(const float*)(lds + LDS_BIH + (256+h)*4);
      c_bhn[r] = *(const float*)(lds + LDS_BHH + (256+h)*4);
    }
    #pragma unroll
    for (int lt=0; lt<8; ++lt){
      int l = lt*16 + n16;
      float rs = *(const float*)(lds + LDS_RSA + l*4);
      uint32_t a_nf = sw(l, h0 + q*4);
      ushortx4 old4 = *(const ushortx4*)(lds + LDS_NFROW + a_nf);
      ushortx4 new4;
      #pragma unroll
      for (int r=0; r<4; ++r){
        float xr = aR[lt][r] + rs*c_gr[r] + c_br[r];
        float xz = aZ[lt][r] + rs*c_gz[r] + c_bz[r];
        float rg = fast_sigmoid(xr);
        float zg = fast_sigmoid(xz);
        float xn = (aGN[lt][r] + rs*c_gn[r] + c_bin[r]) + rg*(aHN[lt][r] + c_bhn[r]);
        float ng = fast_tanh(xn);
        float hv = bf2f(old4[r]);
        new4[r] = f2bf(ng + zg*(hv - ng));
      }
      *(ushortx4*)(lds + LDS_NFROW + a_nf) = new4;
      #pragma unroll
      for (int r=0; r<4; ++r)
        *(unsigned short*)(lds + LDS_NFT + sw(h0 + q*4 + r, l)) = new4[r];
    }
    __syncthreads();
  }

  // ===== MLP: h1 = tanh(nf@mW1^T + mb1) -> LDS_P =====
  {
    f32x4 acc[4][2];
    #pragma unroll
    for (int a=0; a<4; ++a){ acc[a][0] = zf4; acc[a][1] = zf4; }
    for (int ks=0; ks<4; ++ks){
      int koff = ks*32 + q*8;
      bf16x8 af[4];
      #pragma unroll
      for (int tt=0; tt<4; ++tt)
        af[tt] = *(const bf16x8*)(mw1b + (size_t)(t0 + tt*16 + n16)*128 + koff);
      #pragma unroll
      for (int lb=0; lb<2; ++lb){
        int l = l0 + lb*16 + n16;
        bf16x8 bb = *(const bf16x8*)(lds + LDS_NFROW + sw(l, koff));
        #pragma unroll
        for (int tt=0; tt<4; ++tt)
          acc[tt][lb] = __builtin_amdgcn_mfma_f32_16x16x32_bf16(af[tt], bb, acc[tt][lb], 0,0,0);
      }
    }
    #pragma unroll
    for (int tt=0; tt<4; ++tt){
      #pragma unroll
      for (int lb=0; lb<2; ++lb){
        int l  = l0 + lb*16 + n16;
        int ob = t0 + tt*16 + q*4;
        ushortx4 o4;
        #pragma unroll
        for (int r=0; r<4; ++r){
          float bsv = *(const float*)(lds + LDS_MB1 + (ob + r)*4);
          o4[r] = f2bf(fast_tanh(acc[tt][lb][r] + bsv));
        }
        *(ushortx4*)(lds + LDS_P + sw(l, ob)) = o4;
      }
    }
  }
  __syncthreads();

  // ===== h2 = tanh(h1@mW2^T + mb2) -> LDS_NFT region =====
  {
    f32x4 acc[4][2];
    #pragma unroll
    for (int a=0; a<4; ++a){ acc[a][0] = zf4; acc[a][1] = zf4; }
    for (int ks=0; ks<4; ++ks){
      int koff = ks*32 + q*8;
      bf16x8 af[4];
      #pragma unroll
      for (int tt=0; tt<4; ++tt)
        af[tt] = *(const bf16x8*)(mw2b + (size_t)(t0 + tt*16 + n16)*128 + koff);
      #pragma unroll
      for (int lb=0; lb<2; ++lb){
        int l = l0 + lb*16 + n16;
        bf16x8 bb = *(const bf16x8*)(lds + LDS_P + sw(l, koff));
        #pragma unroll
        for (int tt=0; tt<4; ++tt)
          acc[tt][lb] = __builtin_amdgcn_mfma_f32_16x16x32_bf16(af[tt], bb, acc[tt][lb], 0,0,0);
      }
    }
    #pragma unroll
    for (int tt=0; tt<4; ++tt){
      #pragma unroll
      for (int lb=0; lb<2; ++lb){
        int l  = l0 + lb*16 + n16;
        int ob = t0 + tt*16 + q*4;
        ushortx4 o4;
        #pragma unroll
        for (int r=0; r<4; ++r){
          float bsv = *(const float*)(lds + LDS_MB2 + (ob + r)*4);
          o4[r] = f2bf(fast_tanh(acc[tt][lb][r] + bsv));
        }
        *(ushortx4*)(lds + LDS_NFT + sw(l, ob)) = o4;
      }
    }
  }
  __syncthreads();

  // ===== final: score[l] = tanh(h2[l]·mW3 + mb3) =====
  {
    int l = tid >> 2, p4 = tid & 3;
    float dot = 0.f;
    #pragma unroll
    for (int c=0; c<4; ++c){
      int o = p4*32 + c*8;
      union{ bf16x8 v; unsigned short s8[8]; } u;
      u.v = *(const bf16x8*)(lds + LDS_NFT + sw(l, o));
      float4 w0 = *(const float4*)(mW3 + o);
      float4 w1 = *(const float4*)(mW3 + o + 4);
      dot += bf2f(u.s8[0])*w0.x + bf2f(u.s8[1])*w0.y + bf2f(u.s8[2])*w0.z + bf2f(u.s8[3])*w0.w
           + bf2f(u.s8[4])*w1.x + bf2f(u.s8[5])*w1.y + bf2f(u.s8[6])*w1.z + bf2f(u.s8[7])*w1.w;
    }
    dot += __shfl_xor(dot, 1);
    dot += __shfl_xor(dot, 2);
    if (p4 == 0) out[bs*128 + l] = fast_tanh(dot + mb3[0]);
  }
}

extern "C" void kernel_launch(void* const* d_in, const int* in_sizes, int n_in,
                              void* d_out, int out_size, void* d_ws, size_t ws_size,
                              hipStream_t stream)
{
  const int*   iv   = (const int*)  d_in[0];
  const float* adj  = (const float*)d_in[1];
  const float* emb  = (const float*)d_in[2];
  const float* gnnw = (const float*)d_in[3];
  const float* gnnb = (const float*)d_in[4];
  const float* Wih  = (const float*)d_in[5];
  const float* Whh  = (const float*)d_in[6];
  const float* bihp = (const float*)d_in[7];
  const float* bhhp = (const float*)d_in[8];
  const float* mW1  = (const float*)d_in[9];
  const float* mb1  = (const float*)d_in[10];
  const float* mW2  = (const float*)d_in[11];
  const float* mb2  = (const float*)d_in[12];
  const float* mW3  = (const float*)d_in[13];
  const float* mb3  = (const float*)d_in[14];
  float* out = (float*)d_out;

  char* ws = (char*)d_ws;
  unsigned short* gw2t_w = (unsigned short*)(ws + WS_GW2T);
  unsigned short* whhb_w = (unsigned short*)(ws + WS_WHH);
  unsigned short* mw1b_w = (unsigned short*)(ws + WS_MW1);
  unsigned short* mw2b_w = (unsigned short*)(ws + WS_MW2);
  float*          gb2_w  = (float*)(ws + WS_GB2);

  hipFuncSetAttribute((const void*)gnn_main,
                      hipFuncAttributeMaxDynamicSharedMemorySize, LDS_TOTAL);

  gnn_prep<<<448, 128, 0, stream>>>(Wih, Whh, gnnw, gnnb, mW1, mW2,
                                    gw2t_w, whhb_w, mw1b_w, mw2b_w, gb2_w);

  int nbs = in_sizes[0] / 128;  // B*S = 2048 sentences
  gnn_main<<<nbs, 512, LDS_TOTAL, stream>>>(
      iv, adj, emb, bihp, bhhp, mb1, mb2, mW3, mb3,
      (const __bf16*)gw2t_w, (const __bf16*)whhb_w,
      (const __bf16*)mw1b_w, (const __bf16*)mw2b_w, gb2_w, out);
}